// Round 1
// baseline (300.594 us; speedup 1.0000x reference)
//
#include <hip/hip_runtime.h>

namespace {

constexpr int kN = 100;   // subactors
constexpr int kH = 16;    // hidden
constexpr int kS = 6;     // state
constexpr int kB = 128;   // batch
constexpr int kT = 128;   // time
constexpr int kG = 3 * kH;    // 48 gate rows
constexpr int kNS = kN * kS;  // 600 floats per (b,t) row
constexpr int kNT = 25;       // n-tiles of 4

__device__ __forceinline__ float rcp_fast(float v) {
  return __builtin_amdgcn_rcpf(v);
}
__device__ __forceinline__ float sigm(float v) {
  return rcp_fast(1.0f + __expf(-v));
}
__device__ __forceinline__ float tanh_fast(float v) {
  // tanh(v) = 1 - 2/(1+exp(2v)); exp->inf/0 saturates correctly to +-1
  return 1.0f - 2.0f * rcp_fast(1.0f + __expf(2.0f * v));
}

}  // namespace

// One 64-thread block = 1 wave = 4 groups of 16 lanes.
// Group g handles sequence (b, n = ntile*4+g); lane j = neuron j.
// h lives in a per-group LDS slot (broadcast reads, 2-way bank alias = free).
__global__ __launch_bounds__(64, 3) void actor_fused(
    const float* __restrict__ x, const float* __restrict__ Wih,
    const float* __restrict__ Whh, const float* __restrict__ bih,
    const float* __restrict__ bhh, const float* __restrict__ W1,
    const float* __restrict__ b1, const float* __restrict__ W2,
    const float* __restrict__ b2, const float* __restrict__ W3,
    const float* __restrict__ b3, float* __restrict__ out) {
  __shared__ float sh[4 * kH];  // per-group h
  __shared__ float sy[4 * kH];  // per-group y1

  const int tid = (int)threadIdx.x;
  const int g = tid >> 4;
  const int j = tid & 15;
  const int b = (int)blockIdx.x / kNT;
  const int n = ((int)blockIdx.x % kNT) * 4 + g;

  // ---- per-lane weights into registers ----
  float wr[kH], wz[kH], wn[kH];
  {
    const float4* p = (const float4*)(Whh + (size_t)n * kG * kH);
#pragma unroll
    for (int c = 0; c < 4; ++c) {
      float4 v = p[j * 4 + c];
      wr[4 * c + 0] = v.x; wr[4 * c + 1] = v.y;
      wr[4 * c + 2] = v.z; wr[4 * c + 3] = v.w;
    }
#pragma unroll
    for (int c = 0; c < 4; ++c) {
      float4 v = p[(kH + j) * 4 + c];
      wz[4 * c + 0] = v.x; wz[4 * c + 1] = v.y;
      wz[4 * c + 2] = v.z; wz[4 * c + 3] = v.w;
    }
#pragma unroll
    for (int c = 0; c < 4; ++c) {
      float4 v = p[(2 * kH + j) * 4 + c];
      wn[4 * c + 0] = v.x; wn[4 * c + 1] = v.y;
      wn[4 * c + 2] = v.z; wn[4 * c + 3] = v.w;
    }
  }

  float ur[kS], uz[kS], un[kS];
  {
    const float* p = Wih + (size_t)n * kG * kS;
#pragma unroll
    for (int s2 = 0; s2 < kS; ++s2) {
      ur[s2] = p[j * kS + s2];
      uz[s2] = p[(kH + j) * kS + s2];
      un[s2] = p[(2 * kH + j) * kS + s2];
    }
  }

  const float* bi = bih + n * kG;
  const float* bh = bhh + n * kG;
  const float br = bi[j] + bh[j];              // r-gate bias (bih+bhh folded)
  const float bz = bi[kH + j] + bh[kH + j];    // z-gate bias folded
  const float bnx = bi[2 * kH + j];            // n-gate input bias
  const float bnh = bh[2 * kH + j];            // n-gate hidden bias (inside r*)

  float w1r[kH], w2r[kH];
  {
    const float4* p1 = (const float4*)(W1 + (size_t)n * kH * kH + j * kH);
    const float4* p2 = (const float4*)(W2 + (size_t)n * kH * kH + j * kH);
#pragma unroll
    for (int c = 0; c < 4; ++c) {
      float4 v = p1[c];
      w1r[4 * c + 0] = v.x; w1r[4 * c + 1] = v.y;
      w1r[4 * c + 2] = v.z; w1r[4 * c + 3] = v.w;
      float4 u = p2[c];
      w2r[4 * c + 0] = u.x; w2r[4 * c + 1] = u.y;
      w2r[4 * c + 2] = u.z; w2r[4 * c + 3] = u.w;
    }
  }
  const float w3e = W3[n * kH + j];
  const float b1e = b1[n * kH + j];
  const float b2e = b2[n * kH + j];
  const float b3e = b3[n];

  // ---- init h = 0 ----
  sh[g * kH + j] = 0.0f;
  float hown = 0.0f;
  asm volatile("s_waitcnt lgkmcnt(0)" ::: "memory");

  const float* xq = x + ((size_t)b * kT * kN + n) * kS;
  float* op = out + ((size_t)n * kB + b) * kT;
  const float4* hv = (const float4*)(sh + g * kH);
  const float4* yv = (const float4*)(sy + g * kH);

#pragma unroll 4
  for (int t = 0; t < kT; ++t) {
    const float* xt = xq + (size_t)t * kNS;
    const float2 xa = *(const float2*)(xt + 0);
    const float2 xb = *(const float2*)(xt + 2);
    const float2 xc = *(const float2*)(xt + 4);

    float ar = br, az = bz, an = bnx;
    ar += xa.x * ur[0] + xa.y * ur[1] + xb.x * ur[2] + xb.y * ur[3] +
          xc.x * ur[4] + xc.y * ur[5];
    az += xa.x * uz[0] + xa.y * uz[1] + xb.x * uz[2] + xb.y * uz[3] +
          xc.x * uz[4] + xc.y * uz[5];
    an += xa.x * un[0] + xa.y * un[1] + xb.x * un[2] + xb.y * un[3] +
          xc.x * un[4] + xc.y * un[5];

    // hh matvec from broadcast LDS h (old h)
    float hr = 0.0f, hz = 0.0f, hn = bnh;
#pragma unroll
    for (int c = 0; c < 4; ++c) {
      const float4 hc = hv[c];
      hr += hc.x * wr[4 * c + 0] + hc.y * wr[4 * c + 1] +
            hc.z * wr[4 * c + 2] + hc.w * wr[4 * c + 3];
      hz += hc.x * wz[4 * c + 0] + hc.y * wz[4 * c + 1] +
            hc.z * wz[4 * c + 2] + hc.w * wz[4 * c + 3];
      hn += hc.x * wn[4 * c + 0] + hc.y * wn[4 * c + 1] +
            hc.z * wn[4 * c + 2] + hc.w * wn[4 * c + 3];
    }

    const float r = sigm(ar + hr);
    const float z = sigm(az + hz);
    const float nnv = tanh_fast(an + r * hn);
    hown = nnv + z * (hown - nnv);  // (1-z)*n + z*h

    sh[g * kH + j] = hown;
    asm volatile("s_waitcnt lgkmcnt(0)" ::: "memory");

    // MLP layer 1 from new h
    float y1 = b1e;
#pragma unroll
    for (int c = 0; c < 4; ++c) {
      const float4 hc = hv[c];
      y1 += hc.x * w1r[4 * c + 0] + hc.y * w1r[4 * c + 1] +
            hc.z * w1r[4 * c + 2] + hc.w * w1r[4 * c + 3];
    }
    y1 = fmaxf(y1, 0.0f);

    sy[g * kH + j] = y1;
    asm volatile("s_waitcnt lgkmcnt(0)" ::: "memory");

    // MLP layer 2
    float y2 = b2e;
#pragma unroll
    for (int c = 0; c < 4; ++c) {
      const float4 yc = yv[c];
      y2 += yc.x * w2r[4 * c + 0] + yc.y * w2r[4 * c + 1] +
            yc.z * w2r[4 * c + 2] + yc.w * w2r[4 * c + 3];
    }
    y2 = fmaxf(y2, 0.0f);

    // MLP layer 3: dot over 16 lanes (butterfly in-group)
    float pr = y2 * w3e;
    pr += __shfl_xor(pr, 1, 16);
    pr += __shfl_xor(pr, 2, 16);
    pr += __shfl_xor(pr, 4, 16);
    pr += __shfl_xor(pr, 8, 16);
    const float y3 = fmaxf(pr + b3e, 0.0f);
    if (j == 0) op[t] = y3;
  }
}

extern "C" void kernel_launch(void* const* d_in, const int* in_sizes, int n_in,
                              void* d_out, int out_size, void* d_ws,
                              size_t ws_size, hipStream_t stream) {
  const float* x = (const float*)d_in[0];
  const float* Wih = (const float*)d_in[1];
  const float* Whh = (const float*)d_in[2];
  const float* bih = (const float*)d_in[3];
  const float* bhh = (const float*)d_in[4];
  const float* W1 = (const float*)d_in[5];
  const float* b1 = (const float*)d_in[6];
  const float* W2 = (const float*)d_in[7];
  const float* b2 = (const float*)d_in[8];
  const float* W3 = (const float*)d_in[9];
  const float* b3 = (const float*)d_in[10];
  float* out = (float*)d_out;

  dim3 grid(kB * kNT);  // 3200 blocks, one wave each
  dim3 block(64);
  actor_fused<<<grid, block, 0, stream>>>(x, Wih, Whh, bih, bhh, W1, b1, W2,
                                          b2, W3, b3, out);
}

// Round 2
// 252.041 us; speedup vs baseline: 1.1926x; 1.1926x over previous
//
#include <hip/hip_runtime.h>

namespace {

constexpr int kN = 100;   // subactors
constexpr int kH = 16;    // hidden
constexpr int kS = 6;     // state
constexpr int kB = 128;   // batch
constexpr int kT = 128;   // time
constexpr int kG = 3 * kH;    // 48 gate rows
constexpr int kNS = kN * kS;  // 600 floats per (b,t) row
constexpr int kNT = 25;       // n-tiles of 4
constexpr size_t kHBytes = (size_t)kB * kT * kN * kH * sizeof(float);  // 105 MB

typedef float vf2 __attribute__((ext_vector_type(2)));

__device__ __forceinline__ vf2 pkfma(vf2 a, vf2 b, vf2 c) {
  return __builtin_elementwise_fma(a, b, c);
}

__device__ __forceinline__ float rcp_fast(float v) {
  return __builtin_amdgcn_rcpf(v);
}
__device__ __forceinline__ float sigm(float v) {
  return rcp_fast(1.0f + __expf(-v));
}
__device__ __forceinline__ float tanh_fast(float v) {
  // tanh(v) = 1 - 2/(1+exp(2v)); exp->inf/0 saturates correctly to +-1
  return 1.0f - 2.0f * rcp_fast(1.0f + __expf(2.0f * v));
}

}  // namespace

// ---------------------------------------------------------------------------
// Kernel A: GRU recurrence only. One wave = 4 groups of 16 lanes; group g
// handles sequence (b, n); lane j = neuron j. h broadcast via per-group LDS
// slot (single round-trip per step). x is prefetched 2 steps ahead so the
// lgkmcnt clobber can't serialize the global load. h_t streamed to hseq.
// ---------------------------------------------------------------------------
__global__ __launch_bounds__(64) void gru_rec(
    const float* __restrict__ x, const float* __restrict__ Wih,
    const float* __restrict__ Whh, const float* __restrict__ bih,
    const float* __restrict__ bhh, float* __restrict__ hseq) {
  __shared__ float sh[4 * kH];

  const int tid = (int)threadIdx.x;
  const int g = tid >> 4;
  const int j = tid & 15;
  const int b = (int)blockIdx.x / kNT;
  const int n = ((int)blockIdx.x % kNT) * 4 + g;

  // ---- per-lane weights (vf2-packed for v_pk_fma_f32) ----
  vf2 wr[8], wz[8], wn[8];
  {
    const float4* p = (const float4*)(Whh + (size_t)n * kG * kH);
#pragma unroll
    for (int c = 0; c < 4; ++c) {
      float4 v = p[j * 4 + c];
      wr[2 * c + 0] = (vf2){v.x, v.y};
      wr[2 * c + 1] = (vf2){v.z, v.w};
    }
#pragma unroll
    for (int c = 0; c < 4; ++c) {
      float4 v = p[(kH + j) * 4 + c];
      wz[2 * c + 0] = (vf2){v.x, v.y};
      wz[2 * c + 1] = (vf2){v.z, v.w};
    }
#pragma unroll
    for (int c = 0; c < 4; ++c) {
      float4 v = p[(2 * kH + j) * 4 + c];
      wn[2 * c + 0] = (vf2){v.x, v.y};
      wn[2 * c + 1] = (vf2){v.z, v.w};
    }
  }

  vf2 ur[3], uz[3], un[3];
  {
    const float* p = Wih + (size_t)n * kG * kS;
#pragma unroll
    for (int s2 = 0; s2 < 3; ++s2) {
      ur[s2] = (vf2){p[j * kS + 2 * s2], p[j * kS + 2 * s2 + 1]};
      uz[s2] = (vf2){p[(kH + j) * kS + 2 * s2], p[(kH + j) * kS + 2 * s2 + 1]};
      un[s2] =
          (vf2){p[(2 * kH + j) * kS + 2 * s2], p[(2 * kH + j) * kS + 2 * s2 + 1]};
    }
  }

  const float* bi = bih + n * kG;
  const float* bh = bhh + n * kG;
  const float br = bi[j] + bh[j];
  const float bz = bi[kH + j] + bh[kH + j];
  const float bnx = bi[2 * kH + j];
  const float bnh = bh[2 * kH + j];

  const float* xq = x + ((size_t)b * kT * kN + n) * kS;
  float* hq = hseq + ((size_t)b * kT * kN + n) * kH + j;

  // ---- x pipeline, depth 2 ----
  vf2 xc0, xc1, xc2;  // x_t
  vf2 xn0, xn1, xn2;  // x_{t+1}
  {
    const float2 a = *(const float2*)(xq + 0);
    const float2 b2_ = *(const float2*)(xq + 2);
    const float2 c = *(const float2*)(xq + 4);
    xc0 = (vf2){a.x, a.y}; xc1 = (vf2){b2_.x, b2_.y}; xc2 = (vf2){c.x, c.y};
    const float2 a2 = *(const float2*)(xq + kNS + 0);
    const float2 b3_ = *(const float2*)(xq + kNS + 2);
    const float2 c2 = *(const float2*)(xq + kNS + 4);
    xn0 = (vf2){a2.x, a2.y}; xn1 = (vf2){b3_.x, b3_.y}; xn2 = (vf2){c2.x, c2.y};
  }

  vf2 h2[8];
#pragma unroll
  for (int k = 0; k < 8; ++k) h2[k] = (vf2){0.0f, 0.0f};
  float hown = 0.0f;

  for (int t = 0; t < kT; ++t) {
    // prefetch x_{t+2} (clamped; issued before any compute/clobber this iter)
    const int tp = (t + 2 < kT) ? (t + 2) : (kT - 1);
    const float* xp = xq + (size_t)tp * kNS;
    const float2 pa = *(const float2*)(xp + 0);
    const float2 pb = *(const float2*)(xp + 2);
    const float2 pc = *(const float2*)(xp + 4);

    // input projection (x_t)
    vf2 tr = pkfma(xc1, ur[1], xc2 * ur[2]);
    tr = pkfma(xc0, ur[0], tr);
    vf2 tz = pkfma(xc1, uz[1], xc2 * uz[2]);
    tz = pkfma(xc0, uz[0], tz);
    vf2 tn = pkfma(xc1, un[1], xc2 * un[2]);
    tn = pkfma(xc0, un[0], tn);

    // hh matvec from broadcast h
    vf2 hr2 = (vf2){0.0f, 0.0f}, hz2 = (vf2){0.0f, 0.0f},
        hn2 = (vf2){0.0f, 0.0f};
#pragma unroll
    for (int k = 0; k < 8; ++k) {
      hr2 = pkfma(h2[k], wr[k], hr2);
      hz2 = pkfma(h2[k], wz[k], hz2);
      hn2 = pkfma(h2[k], wn[k], hn2);
    }

    const float ar = br + tr.x + tr.y + hr2.x + hr2.y;
    const float az = bz + tz.x + tz.y + hz2.x + hz2.y;
    const float r = sigm(ar);
    const float z = sigm(az);
    const float nnv = tanh_fast(bnx + tn.x + tn.y + r * (bnh + hn2.x + hn2.y));
    hown = nnv + z * (hown - nnv);

    sh[g * kH + j] = hown;
    hq[(size_t)t * kN * kH] = hown;  // fire-and-forget stream of h_t
    asm volatile("s_waitcnt lgkmcnt(0)" ::: "memory");

    const float4* hvp = (const float4*)(sh + g * kH);
#pragma unroll
    for (int c = 0; c < 4; ++c) {
      const float4 v = hvp[c];
      h2[2 * c + 0] = (vf2){v.x, v.y};
      h2[2 * c + 1] = (vf2){v.z, v.w};
    }

    // rotate x pipeline
    xc0 = xn0; xc1 = xn1; xc2 = xn2;
    xn0 = (vf2){pa.x, pa.y}; xn1 = (vf2){pb.x, pb.y}; xn2 = (vf2){pc.x, pc.y};
  }
}

// ---------------------------------------------------------------------------
// Kernel B: MLP head, embarrassingly parallel over (b,t,n).
// Block = 256 threads = 16 groups of 16 lanes; block handles one n and
// 16*8 = 128 (b,t) pairs. Groups never cross waves -> no __syncthreads.
// ---------------------------------------------------------------------------
__global__ __launch_bounds__(256) void mlp_head(
    const float* __restrict__ hseq, const float* __restrict__ W1,
    const float* __restrict__ b1, const float* __restrict__ W2,
    const float* __restrict__ b2, const float* __restrict__ W3,
    const float* __restrict__ b3, float* __restrict__ out) {
  __shared__ float sbuf[16 * 16];

  const int tid = (int)threadIdx.x;
  const int j = tid & 15;
  const int gg = tid >> 4;
  const int n = (int)blockIdx.y;

  vf2 w1[8], w2[8];
  {
    const float4* p1 = (const float4*)(W1 + (size_t)n * kH * kH + j * kH);
    const float4* p2 = (const float4*)(W2 + (size_t)n * kH * kH + j * kH);
#pragma unroll
    for (int c = 0; c < 4; ++c) {
      float4 v = p1[c];
      w1[2 * c + 0] = (vf2){v.x, v.y};
      w1[2 * c + 1] = (vf2){v.z, v.w};
      float4 u = p2[c];
      w2[2 * c + 0] = (vf2){u.x, u.y};
      w2[2 * c + 1] = (vf2){u.z, u.w};
    }
  }
  const float w3e = W3[n * kH + j];
  const float b1e = b1[n * kH + j];
  const float b2e = b2[n * kH + j];
  const float b3e = b3[n];

  const int bt0 = (int)blockIdx.x * 128 + gg;
  const float* sb = sbuf + gg * 16;
  const float4* sv = (const float4*)sb;

#pragma unroll 2
  for (int it = 0; it < 8; ++it) {
    const int bt = bt0 + it * 16;
    const float hv = hseq[((size_t)bt * kN + n) * kH + j];

    sbuf[gg * 16 + j] = hv;
    asm volatile("s_waitcnt lgkmcnt(0)" ::: "memory");

    vf2 a1 = (vf2){0.0f, 0.0f};
#pragma unroll
    for (int c = 0; c < 4; ++c) {
      const float4 v = sv[c];
      a1 = pkfma((vf2){v.x, v.y}, w1[2 * c + 0], a1);
      a1 = pkfma((vf2){v.z, v.w}, w1[2 * c + 1], a1);
    }
    const float y1 = fmaxf(b1e + a1.x + a1.y, 0.0f);

    sbuf[gg * 16 + j] = y1;
    asm volatile("s_waitcnt lgkmcnt(0)" ::: "memory");

    vf2 a2 = (vf2){0.0f, 0.0f};
#pragma unroll
    for (int c = 0; c < 4; ++c) {
      const float4 v = sv[c];
      a2 = pkfma((vf2){v.x, v.y}, w2[2 * c + 0], a2);
      a2 = pkfma((vf2){v.z, v.w}, w2[2 * c + 1], a2);
    }
    const float y2 = fmaxf(b2e + a2.x + a2.y, 0.0f);

    float pr = y2 * w3e;
    pr += __shfl_xor(pr, 1, 16);
    pr += __shfl_xor(pr, 2, 16);
    pr += __shfl_xor(pr, 4, 16);
    pr += __shfl_xor(pr, 8, 16);
    if (j == 0) {
      const int bb = bt >> 7;
      const int tt = bt & 127;
      out[((size_t)n * kB + bb) * kT + tt] = fmaxf(pr + b3e, 0.0f);
    }
  }
}

// ---------------------------------------------------------------------------
// Fallback: round-1 fused kernel (used only if ws_size is too small).
// ---------------------------------------------------------------------------
__global__ __launch_bounds__(64, 3) void actor_fused(
    const float* __restrict__ x, const float* __restrict__ Wih,
    const float* __restrict__ Whh, const float* __restrict__ bih,
    const float* __restrict__ bhh, const float* __restrict__ W1,
    const float* __restrict__ b1, const float* __restrict__ W2,
    const float* __restrict__ b2, const float* __restrict__ W3,
    const float* __restrict__ b3, float* __restrict__ out) {
  __shared__ float sh[4 * kH];
  __shared__ float sy[4 * kH];

  const int tid = (int)threadIdx.x;
  const int g = tid >> 4;
  const int j = tid & 15;
  const int b = (int)blockIdx.x / kNT;
  const int n = ((int)blockIdx.x % kNT) * 4 + g;

  float wr[kH], wz[kH], wn[kH];
  {
    const float4* p = (const float4*)(Whh + (size_t)n * kG * kH);
#pragma unroll
    for (int c = 0; c < 4; ++c) {
      float4 v = p[j * 4 + c];
      wr[4 * c + 0] = v.x; wr[4 * c + 1] = v.y;
      wr[4 * c + 2] = v.z; wr[4 * c + 3] = v.w;
    }
#pragma unroll
    for (int c = 0; c < 4; ++c) {
      float4 v = p[(kH + j) * 4 + c];
      wz[4 * c + 0] = v.x; wz[4 * c + 1] = v.y;
      wz[4 * c + 2] = v.z; wz[4 * c + 3] = v.w;
    }
#pragma unroll
    for (int c = 0; c < 4; ++c) {
      float4 v = p[(2 * kH + j) * 4 + c];
      wn[4 * c + 0] = v.x; wn[4 * c + 1] = v.y;
      wn[4 * c + 2] = v.z; wn[4 * c + 3] = v.w;
    }
  }

  float ur[kS], uz[kS], un[kS];
  {
    const float* p = Wih + (size_t)n * kG * kS;
#pragma unroll
    for (int s2 = 0; s2 < kS; ++s2) {
      ur[s2] = p[j * kS + s2];
      uz[s2] = p[(kH + j) * kS + s2];
      un[s2] = p[(2 * kH + j) * kS + s2];
    }
  }

  const float* bi = bih + n * kG;
  const float* bh = bhh + n * kG;
  const float br = bi[j] + bh[j];
  const float bz = bi[kH + j] + bh[kH + j];
  const float bnx = bi[2 * kH + j];
  const float bnh = bh[2 * kH + j];

  float w1r[kH], w2r[kH];
  {
    const float4* p1 = (const float4*)(W1 + (size_t)n * kH * kH + j * kH);
    const float4* p2 = (const float4*)(W2 + (size_t)n * kH * kH + j * kH);
#pragma unroll
    for (int c = 0; c < 4; ++c) {
      float4 v = p1[c];
      w1r[4 * c + 0] = v.x; w1r[4 * c + 1] = v.y;
      w1r[4 * c + 2] = v.z; w1r[4 * c + 3] = v.w;
      float4 u = p2[c];
      w2r[4 * c + 0] = u.x; w2r[4 * c + 1] = u.y;
      w2r[4 * c + 2] = u.z; w2r[4 * c + 3] = u.w;
    }
  }
  const float w3e = W3[n * kH + j];
  const float b1e = b1[n * kH + j];
  const float b2e = b2[n * kH + j];
  const float b3e = b3[n];

  sh[g * kH + j] = 0.0f;
  float hown = 0.0f;
  asm volatile("s_waitcnt lgkmcnt(0)" ::: "memory");

  const float* xq = x + ((size_t)b * kT * kN + n) * kS;
  float* op = out + ((size_t)n * kB + b) * kT;
  const float4* hv = (const float4*)(sh + g * kH);
  const float4* yv = (const float4*)(sy + g * kH);

#pragma unroll 4
  for (int t = 0; t < kT; ++t) {
    const float* xt = xq + (size_t)t * kNS;
    const float2 xa = *(const float2*)(xt + 0);
    const float2 xb = *(const float2*)(xt + 2);
    const float2 xc = *(const float2*)(xt + 4);

    float ar = br, az = bz, an = bnx;
    ar += xa.x * ur[0] + xa.y * ur[1] + xb.x * ur[2] + xb.y * ur[3] +
          xc.x * ur[4] + xc.y * ur[5];
    az += xa.x * uz[0] + xa.y * uz[1] + xb.x * uz[2] + xb.y * uz[3] +
          xc.x * uz[4] + xc.y * uz[5];
    an += xa.x * un[0] + xa.y * un[1] + xb.x * un[2] + xb.y * un[3] +
          xc.x * un[4] + xc.y * un[5];

    float hr = 0.0f, hz = 0.0f, hn = bnh;
#pragma unroll
    for (int c = 0; c < 4; ++c) {
      const float4 hc = hv[c];
      hr += hc.x * wr[4 * c + 0] + hc.y * wr[4 * c + 1] +
            hc.z * wr[4 * c + 2] + hc.w * wr[4 * c + 3];
      hz += hc.x * wz[4 * c + 0] + hc.y * wz[4 * c + 1] +
            hc.z * wz[4 * c + 2] + hc.w * wz[4 * c + 3];
      hn += hc.x * wn[4 * c + 0] + hc.y * wn[4 * c + 1] +
            hc.z * wn[4 * c + 2] + hc.w * wn[4 * c + 3];
    }

    const float r = sigm(ar + hr);
    const float z = sigm(az + hz);
    const float nnv = tanh_fast(an + r * hn);
    hown = nnv + z * (hown - nnv);

    sh[g * kH + j] = hown;
    asm volatile("s_waitcnt lgkmcnt(0)" ::: "memory");

    float y1 = b1e;
#pragma unroll
    for (int c = 0; c < 4; ++c) {
      const float4 hc = hv[c];
      y1 += hc.x * w1r[4 * c + 0] + hc.y * w1r[4 * c + 1] +
            hc.z * w1r[4 * c + 2] + hc.w * w1r[4 * c + 3];
    }
    y1 = fmaxf(y1, 0.0f);

    sy[g * kH + j] = y1;
    asm volatile("s_waitcnt lgkmcnt(0)" ::: "memory");

    float y2 = b2e;
#pragma unroll
    for (int c = 0; c < 4; ++c) {
      const float4 yc = yv[c];
      y2 += yc.x * w2r[4 * c + 0] + yc.y * w2r[4 * c + 1] +
            yc.z * w2r[4 * c + 2] + yc.w * w2r[4 * c + 3];
    }
    y2 = fmaxf(y2, 0.0f);

    float pr = y2 * w3e;
    pr += __shfl_xor(pr, 1, 16);
    pr += __shfl_xor(pr, 2, 16);
    pr += __shfl_xor(pr, 4, 16);
    pr += __shfl_xor(pr, 8, 16);
    const float y3 = fmaxf(pr + b3e, 0.0f);
    if (j == 0) op[t] = y3;
  }
}

extern "C" void kernel_launch(void* const* d_in, const int* in_sizes, int n_in,
                              void* d_out, int out_size, void* d_ws,
                              size_t ws_size, hipStream_t stream) {
  const float* x = (const float*)d_in[0];
  const float* Wih = (const float*)d_in[1];
  const float* Whh = (const float*)d_in[2];
  const float* bih = (const float*)d_in[3];
  const float* bhh = (const float*)d_in[4];
  const float* W1 = (const float*)d_in[5];
  const float* b1 = (const float*)d_in[6];
  const float* W2 = (const float*)d_in[7];
  const float* b2 = (const float*)d_in[8];
  const float* W3 = (const float*)d_in[9];
  const float* b3 = (const float*)d_in[10];
  float* out = (float*)d_out;

  if (ws_size >= kHBytes) {
    float* hseq = (float*)d_ws;
    gru_rec<<<dim3(kB * kNT), dim3(64), 0, stream>>>(x, Wih, Whh, bih, bhh,
                                                     hseq);
    mlp_head<<<dim3(kB * kT / 128, kN), dim3(256), 0, stream>>>(
        hseq, W1, b1, W2, b2, W3, b3, out);
  } else {
    actor_fused<<<dim3(kB * kNT), dim3(64), 0, stream>>>(
        x, Wih, Whh, bih, bhh, W1, b1, W2, b2, W3, b3, out);
  }
}

// Round 3
// 228.635 us; speedup vs baseline: 1.3147x; 1.1024x over previous
//
#include <hip/hip_runtime.h>

namespace {

constexpr int kN = 100;   // subactors
constexpr int kH = 16;    // hidden
constexpr int kS = 6;     // state
constexpr int kB = 128;   // batch
constexpr int kT = 128;   // time
constexpr int kG = 3 * kH;    // 48 gate rows
constexpr int kNS = kN * kS;  // 600 floats per (b,t) row
constexpr int kNT = 25;       // n-tiles of 4

typedef float vf2 __attribute__((ext_vector_type(2)));

__device__ __forceinline__ vf2 pkfma(vf2 a, vf2 b, vf2 c) {
  return __builtin_elementwise_fma(a, b, c);
}

__device__ __forceinline__ float rcp_fast(float v) {
  return __builtin_amdgcn_rcpf(v);
}
__device__ __forceinline__ float sigm(float v) {
  return rcp_fast(1.0f + __expf(-v));
}
__device__ __forceinline__ float tanh_fast(float v) {
  return 1.0f - 2.0f * rcp_fast(1.0f + __expf(2.0f * v));
}

// ---- DPP cross-lane (VALU pipe, no LDS) ----
// quad_perm broadcast of quad-pos m: all 4 selects = m -> ctrl = m*0x55.
// row_ror:N = 0x120+N, rotates within each 16-lane row (our group == row).
constexpr int kQP0 = 0x00, kQP1 = 0x55, kQP2 = 0xAA, kQP3 = 0xFF;
constexpr int kROR1 = 0x121, kROR2 = 0x122, kROR4 = 0x124, kROR8 = 0x128,
              kROR12 = 0x12C;

template <int CTRL>
__device__ __forceinline__ int dppi(int v) {
  return __builtin_amdgcn_update_dpp(0, v, CTRL, 0xF, 0xF, true);
}
template <int CTRL>
__device__ __forceinline__ float dppf(float v) {
  return __builtin_bit_cast(float,
                            dppi<CTRL>(__builtin_bit_cast(int, v)));
}

// All-gather 16 scalars (one per lane of the row) into 8 vf2 per lane.
// Slot m holds the 4 values of quad bq[m] (bq = runtime probe order, so the
// layout is correct regardless of the HW rotate direction).
__device__ __forceinline__ void allgather16(float v, vf2 o[8]) {
  const float q0 = dppf<kQP0>(v);
  const float q1 = dppf<kQP1>(v);
  const float q2 = dppf<kQP2>(v);
  const float q3 = dppf<kQP3>(v);
  o[0] = (vf2){q0, q1};
  o[1] = (vf2){q2, q3};
  o[2] = (vf2){dppf<kROR4>(q0), dppf<kROR4>(q1)};
  o[3] = (vf2){dppf<kROR4>(q2), dppf<kROR4>(q3)};
  o[4] = (vf2){dppf<kROR8>(q0), dppf<kROR8>(q1)};
  o[5] = (vf2){dppf<kROR8>(q2), dppf<kROR8>(q3)};
  o[6] = (vf2){dppf<kROR12>(q0), dppf<kROR12>(q1)};
  o[7] = (vf2){dppf<kROR12>(q2), dppf<kROR12>(q3)};
}

// Sum of the 16 scalars of the row (every lane gets the total).
// Rotate-reduce: direction-agnostic.
__device__ __forceinline__ float rowsum16(float v) {
  v += dppf<kROR1>(v);
  v += dppf<kROR2>(v);
  v += dppf<kROR4>(v);
  v += dppf<kROR8>(v);
  return v;
}

__device__ __forceinline__ float dot8(const vf2 w[8], const vf2 h[8]) {
  vf2 a = w[0] * h[0];
  a = pkfma(w[1], h[1], a);
  a = pkfma(w[2], h[2], a);
  a = pkfma(w[3], h[3], a);
  a = pkfma(w[4], h[4], a);
  a = pkfma(w[5], h[5], a);
  a = pkfma(w[6], h[6], a);
  a = pkfma(w[7], h[7], a);
  return a.x + a.y;
}

}  // namespace

// One wave per block; 4 rows of 16 lanes; row g = sequence (b, n), lane j =
// neuron j. No LDS, no barriers: all cross-lane via DPP, x prefetched 4 deep.
__global__ __launch_bounds__(64) void actor_dpp(
    const float* __restrict__ x, const float* __restrict__ Wih,
    const float* __restrict__ Whh, const float* __restrict__ bih,
    const float* __restrict__ bhh, const float* __restrict__ W1,
    const float* __restrict__ b1, const float* __restrict__ W2,
    const float* __restrict__ b2, const float* __restrict__ W3,
    const float* __restrict__ b3, float* __restrict__ out) {
  const int tid = (int)threadIdx.x;
  const int j = tid & 15;
  const int b = (int)blockIdx.x / kNT;
  const int n = ((int)blockIdx.x % kNT) * 4 + (tid >> 4);

  // Runtime probe: which absolute quad lands in slot m after ror(4m).
  const int q = j >> 2;
  int bq[4];
  bq[0] = q;
  bq[1] = dppi<kROR4>(q);
  bq[2] = dppi<kROR8>(q);
  bq[3] = dppi<kROR12>(q);

  // ---- weights, float4 blocks permuted to match the gather slot order ----
  vf2 wr[8], wz[8], wn[8], w1[8], w2[8];
  {
    const float4* whh4 = (const float4*)(Whh + (size_t)n * kG * kH);
    const float4* w14 = (const float4*)(W1 + (size_t)n * kH * kH);
    const float4* w24 = (const float4*)(W2 + (size_t)n * kH * kH);
#pragma unroll
    for (int m = 0; m < 4; ++m) {
      const int bm = bq[m];
      float4 v = whh4[j * 4 + bm];
      wr[2 * m] = (vf2){v.x, v.y};
      wr[2 * m + 1] = (vf2){v.z, v.w};
      v = whh4[(kH + j) * 4 + bm];
      wz[2 * m] = (vf2){v.x, v.y};
      wz[2 * m + 1] = (vf2){v.z, v.w};
      v = whh4[(2 * kH + j) * 4 + bm];
      wn[2 * m] = (vf2){v.x, v.y};
      wn[2 * m + 1] = (vf2){v.z, v.w};
      v = w14[j * 4 + bm];
      w1[2 * m] = (vf2){v.x, v.y};
      w1[2 * m + 1] = (vf2){v.z, v.w};
      v = w24[j * 4 + bm];
      w2[2 * m] = (vf2){v.x, v.y};
      w2[2 * m + 1] = (vf2){v.z, v.w};
    }
  }

  vf2 ur[3], uz[3], un[3];
  {
    const float* p = Wih + (size_t)n * kG * kS;
#pragma unroll
    for (int s2 = 0; s2 < 3; ++s2) {
      ur[s2] = (vf2){p[j * kS + 2 * s2], p[j * kS + 2 * s2 + 1]};
      uz[s2] = (vf2){p[(kH + j) * kS + 2 * s2], p[(kH + j) * kS + 2 * s2 + 1]};
      un[s2] = (vf2){p[(2 * kH + j) * kS + 2 * s2],
                     p[(2 * kH + j) * kS + 2 * s2 + 1]};
    }
  }

  const float* bi = bih + n * kG;
  const float* bh = bhh + n * kG;
  const float br = bi[j] + bh[j];
  const float bz = bi[kH + j] + bh[kH + j];
  const float bnx = bi[2 * kH + j];
  const float bnh = bh[2 * kH + j];
  const float b1e = b1[n * kH + j];
  const float b2e = b2[n * kH + j];
  const float b3e = b3[n];
  const float w3e = W3[n * kH + j];

  const float* xq = x + ((size_t)b * kT * kN + n) * kS;
  float* op = out + ((size_t)n * kB + b) * kT;

  // ---- x pipeline: 4 stages x 3 vf2 ----
  vf2 xs[4][3];
#pragma unroll
  for (int i = 0; i < 4; ++i) {
    const float* xp = xq + (size_t)i * kNS;
    const float2 a = *(const float2*)(xp + 0);
    const float2 c = *(const float2*)(xp + 2);
    const float2 d = *(const float2*)(xp + 4);
    xs[i][0] = (vf2){a.x, a.y};
    xs[i][1] = (vf2){c.x, c.y};
    xs[i][2] = (vf2){d.x, d.y};
  }

  vf2 h2[8];
#pragma unroll
  for (int k = 0; k < 8; ++k) h2[k] = (vf2){0.0f, 0.0f};
  float hown = 0.0f;
  float yb[4];

  for (int t = 0; t < kT; t += 4) {
#pragma unroll
    for (int k = 0; k < 4; ++k) {
      // input projection
      vf2 tr = pkfma(xs[k][0], ur[0], pkfma(xs[k][1], ur[1], xs[k][2] * ur[2]));
      vf2 tz = pkfma(xs[k][0], uz[0], pkfma(xs[k][1], uz[1], xs[k][2] * uz[2]));
      vf2 tn = pkfma(xs[k][0], un[0], pkfma(xs[k][1], un[1], xs[k][2] * un[2]));

      // reload this stage with x_{t+k+4}
      {
        int tp = t + k + 4;
        if (tp > kT - 1) tp = kT - 1;
        const float* xp = xq + (size_t)tp * kNS;
        const float2 a = *(const float2*)(xp + 0);
        const float2 c = *(const float2*)(xp + 2);
        const float2 d = *(const float2*)(xp + 4);
        xs[k][0] = (vf2){a.x, a.y};
        xs[k][1] = (vf2){c.x, c.y};
        xs[k][2] = (vf2){d.x, d.y};
      }

      // hh matvec (3 independent pk_fma chains over the gathered bundle)
      vf2 hr2 = h2[0] * wr[0], hz2 = h2[0] * wz[0], hn2 = h2[0] * wn[0];
#pragma unroll
      for (int m = 1; m < 8; ++m) {
        hr2 = pkfma(h2[m], wr[m], hr2);
        hz2 = pkfma(h2[m], wz[m], hz2);
        hn2 = pkfma(h2[m], wn[m], hn2);
      }

      const float r = sigm(br + tr.x + tr.y + hr2.x + hr2.y);
      const float z = sigm(bz + tz.x + tz.y + hz2.x + hz2.y);
      const float nnv =
          tanh_fast(bnx + tn.x + tn.y + r * (bnh + hn2.x + hn2.y));
      hown = nnv + z * (hown - nnv);

      // broadcast new h to the row (DPP, no LDS)
      allgather16(hown, h2);

      // MLP layer 1
      const float y1 = fmaxf(b1e + dot8(w1, h2), 0.0f);

      // broadcast y1
      vf2 yv[8];
      allgather16(y1, yv);

      // MLP layer 2
      const float y2 = fmaxf(b2e + dot8(w2, yv), 0.0f);

      // MLP layer 3: row-wide dot
      const float s = rowsum16(y2 * w3e);
      yb[k] = fmaxf(s + b3e, 0.0f);
    }
    if (j == 0) {
      *(float4*)(op + t) = (float4){yb[0], yb[1], yb[2], yb[3]};
    }
  }
}

extern "C" void kernel_launch(void* const* d_in, const int* in_sizes, int n_in,
                              void* d_out, int out_size, void* d_ws,
                              size_t ws_size, hipStream_t stream) {
  const float* x = (const float*)d_in[0];
  const float* Wih = (const float*)d_in[1];
  const float* Whh = (const float*)d_in[2];
  const float* bih = (const float*)d_in[3];
  const float* bhh = (const float*)d_in[4];
  const float* W1 = (const float*)d_in[5];
  const float* b1 = (const float*)d_in[6];
  const float* W2 = (const float*)d_in[7];
  const float* b2 = (const float*)d_in[8];
  const float* W3 = (const float*)d_in[9];
  const float* b3 = (const float*)d_in[10];
  float* out = (float*)d_out;

  actor_dpp<<<dim3(kB * kNT), dim3(64), 0, stream>>>(x, Wih, Whh, bih, bhh, W1,
                                                     b1, W2, b2, W3, b3, out);
}

// Round 5
// 167.512 us; speedup vs baseline: 1.7945x; 1.3649x over previous
//
#include <hip/hip_runtime.h>

namespace {

constexpr int kN = 100;   // subactors
constexpr int kH = 16;    // hidden
constexpr int kS = 6;     // state
constexpr int kB = 128;   // batch
constexpr int kT = 128;   // time
constexpr int kNS = kN * kS;      // 600 floats per (b,t) row
constexpr int kXB = kT * kNS;     // 76800 floats per b

typedef float f32x4 __attribute__((ext_vector_type(4)));
typedef short bf16x8 __attribute__((ext_vector_type(8)));

union Frag {
  unsigned u[4];
  bf16x8 v;
};

// RNE pack of two f32 into one dword of two bf16 (low = a). Manual bit twiddle
// (bit-identical to __float2bfloat16_rn for non-NaN) — __hip_bfloat162 is not
// trivially copyable so __builtin_bit_cast on it doesn't compile.
__device__ __forceinline__ unsigned pkbf(float a, float b) {
  unsigned ua = __builtin_bit_cast(unsigned, a);
  unsigned ub = __builtin_bit_cast(unsigned, b);
  ua += 0x7fffu + ((ua >> 16) & 1u);
  ub += 0x7fffu + ((ub >> 16) & 1u);
  return (ua >> 16) | (ub & 0xffff0000u);
}

__device__ __forceinline__ float rcp_fast(float v) {
  return __builtin_amdgcn_rcpf(v);
}
__device__ __forceinline__ float sigm(float v) {
  return rcp_fast(1.0f + __expf(-v));
}
__device__ __forceinline__ float tanh_fast(float v) {
  return 1.0f - 2.0f * rcp_fast(1.0f + __expf(2.0f * v));
}

__device__ __forceinline__ f32x4 mfma16(bf16x8 a, bf16x8 b, f32x4 c) {
  return __builtin_amdgcn_mfma_f32_16x16x32_bf16(a, b, c, 0, 0, 0);
}

}  // namespace

// One wave per block. Wave = (n, batch-tile of 16). Transposed-gate MFMA:
//   C[gate-row 16][batch-col 16] = A_weights[16 x K=32] * B[[h;x] K=32][16 b]
// A layout (verified): m = lane&15, k = (lane>>4)*8 + i.
// B layout (A-mirror):  col = lane&15, k = (lane>>4)*8 + i.
// C layout (verified): col = lane&15 (batch), row = (lane>>4)*4 + reg (gate).
__global__ __launch_bounds__(64) void actor_mfma(
    const float* __restrict__ x, const float* __restrict__ Wih,
    const float* __restrict__ Whh, const float* __restrict__ bih,
    const float* __restrict__ bhh, const float* __restrict__ W1,
    const float* __restrict__ b1, const float* __restrict__ W2,
    const float* __restrict__ b2, const float* __restrict__ W3,
    const float* __restrict__ b3, float* __restrict__ out) {
  const int tid = (int)threadIdx.x;
  const int j = tid & 15;    // batch-col within tile / A-row m
  const int qt = tid >> 4;   // quad index (k-group for A/B, row-group for C)
  const int n = (int)blockIdx.x >> 3;
  const int bt = (int)blockIdx.x & 7;

  // ---- static A fragments (weights), built once ----
  Frag Ar, Az, Anh, Anx, Ay1, Ay2;
  auto mkA = [&](Frag& F, const float* hrow /*16f|null*/,
                 const float* xrow /*6f|null*/) {
    F.u[0] = F.u[1] = F.u[2] = F.u[3] = 0u;
    if (qt == 0 && hrow) {
      F.u[0] = pkbf(hrow[0], hrow[1]);
      F.u[1] = pkbf(hrow[2], hrow[3]);
      F.u[2] = pkbf(hrow[4], hrow[5]);
      F.u[3] = pkbf(hrow[6], hrow[7]);
    }
    if (qt == 1 && hrow) {
      F.u[0] = pkbf(hrow[8], hrow[9]);
      F.u[1] = pkbf(hrow[10], hrow[11]);
      F.u[2] = pkbf(hrow[12], hrow[13]);
      F.u[3] = pkbf(hrow[14], hrow[15]);
    }
    if (qt == 2 && xrow) {  // k 16..21 = x, 22..31 = 0
      F.u[0] = pkbf(xrow[0], xrow[1]);
      F.u[1] = pkbf(xrow[2], xrow[3]);
      F.u[2] = pkbf(xrow[4], xrow[5]);
    }
  };
  mkA(Ar, Whh + ((size_t)n * 48 + j) * 16, Wih + ((size_t)n * 48 + j) * 6);
  mkA(Az, Whh + ((size_t)n * 48 + 16 + j) * 16,
      Wih + ((size_t)n * 48 + 16 + j) * 6);
  mkA(Anh, Whh + ((size_t)n * 48 + 32 + j) * 16, nullptr);
  mkA(Anx, nullptr, Wih + ((size_t)n * 48 + 32 + j) * 6);
  mkA(Ay1, W1 + ((size_t)n * 16 + j) * 16, nullptr);
  mkA(Ay2, W2 + ((size_t)n * 16 + j) * 16, nullptr);

  // ---- per-lane bias/constant regs (C rows 4*qt..4*qt+3) ----
  float br_[4], bz_[4], bin_[4], bhn_[4], b1e[4], b2e[4], w3r[4];
#pragma unroll
  for (int r = 0; r < 4; ++r) {
    const int gi = n * 48 + 4 * qt + r;
    br_[r] = bih[gi] + bhh[gi];
    bz_[r] = bih[gi + 16] + bhh[gi + 16];
    bin_[r] = bih[gi + 32];
    bhn_[r] = bhh[gi + 32];
    const int hi = n * 16 + 4 * qt + r;
    b1e[r] = b1[hi];
    b2e[r] = b2[hi];
    w3r[r] = W3[hi];
  }
  const float b3s = b3[n];

  // bpermute source byte-addrs for B assembly (h rows 8q..8q+7 of col j)
  const int a_lo = (j + 32 * (qt & 1)) * 4;
  const int a_hi = a_lo + 64;

  const int b = bt * 16 + j;
  const float* px = x + (size_t)b * kXB + (size_t)n * kS;
  float* outp = out + ((size_t)n * kB + b) * kT;

  const f32x4 zero4 = {0.f, 0.f, 0.f, 0.f};

  // ---- x register pipeline, depth 4 ----
  float2 xs[4][3];
#pragma unroll
  for (int i = 0; i < 4; ++i) {
    const float* xp = px + (size_t)i * kNS;
    xs[i][0] = *(const float2*)(xp + 0);
    xs[i][1] = *(const float2*)(xp + 2);
    xs[i][2] = *(const float2*)(xp + 4);
  }

  float hprev[4] = {0.f, 0.f, 0.f, 0.f};

  // shared y tail: relu(Cy1+b1) -> B_y1 -> y2 -> y3 -> store[tout]
  auto doY = [&](const f32x4& Cy1, int tout) {
    float y1v[4];
#pragma unroll
    for (int r = 0; r < 4; ++r) y1v[r] = fmaxf(Cy1[r] + b1e[r], 0.f);
    const unsigned Q0 = pkbf(y1v[0], y1v[1]);
    const unsigned Q1 = pkbf(y1v[2], y1v[3]);
    const int yb0 = __builtin_amdgcn_ds_bpermute(a_lo, (int)Q0);
    const int yb1 = __builtin_amdgcn_ds_bpermute(a_lo, (int)Q1);
    const int yb2 = __builtin_amdgcn_ds_bpermute(a_hi, (int)Q0);
    const int yb3 = __builtin_amdgcn_ds_bpermute(a_hi, (int)Q1);
    Frag By;
    By.u[0] = (qt < 2) ? (unsigned)yb0 : 0u;
    By.u[1] = (qt < 2) ? (unsigned)yb1 : 0u;
    By.u[2] = (qt < 2) ? (unsigned)yb2 : 0u;
    By.u[3] = (qt < 2) ? (unsigned)yb3 : 0u;
    const f32x4 Cy2 = mfma16(Ay2.v, By.v, zero4);
    float s = 0.f;
#pragma unroll
    for (int r = 0; r < 4; ++r) s += fmaxf(Cy2[r] + b2e[r], 0.f) * w3r[r];
    s += __shfl_xor(s, 16);
    s += __shfl_xor(s, 32);
    const float y3 = fmaxf(s + b3s, 0.f);
    if (tout >= 0 && qt == 0) outp[tout] = y3;
  };

  auto doStep = [&](int t, int st) {
    // assemble B = [h_{t-1}; x_t]
    const unsigned P0 = pkbf(hprev[0], hprev[1]);
    const unsigned P1 = pkbf(hprev[2], hprev[3]);
    const int bp0 = __builtin_amdgcn_ds_bpermute(a_lo, (int)P0);
    const int bp1 = __builtin_amdgcn_ds_bpermute(a_lo, (int)P1);
    const int bp2 = __builtin_amdgcn_ds_bpermute(a_hi, (int)P0);
    const int bp3 = __builtin_amdgcn_ds_bpermute(a_hi, (int)P1);
    const unsigned xd0 = pkbf(xs[st][0].x, xs[st][0].y);
    const unsigned xd1 = pkbf(xs[st][1].x, xs[st][1].y);
    const unsigned xd2 = pkbf(xs[st][2].x, xs[st][2].y);
    Frag Bf;
    Bf.u[0] = (qt < 2) ? (unsigned)bp0 : ((qt == 2) ? xd0 : 0u);
    Bf.u[1] = (qt < 2) ? (unsigned)bp1 : ((qt == 2) ? xd1 : 0u);
    Bf.u[2] = (qt < 2) ? (unsigned)bp2 : ((qt == 2) ? xd2 : 0u);
    Bf.u[3] = (qt < 2) ? (unsigned)bp3 : 0u;

    // reload this x stage with t+4
    {
      int tc = t + 4;
      if (tc > kT - 1) tc = kT - 1;
      const float* xp = px + (size_t)tc * kNS;
      xs[st][0] = *(const float2*)(xp + 0);
      xs[st][1] = *(const float2*)(xp + 2);
      xs[st][2] = *(const float2*)(xp + 4);
    }

    const f32x4 Cr = mfma16(Ar.v, Bf.v, zero4);    // xr + hr
    const f32x4 Cz = mfma16(Az.v, Bf.v, zero4);    // xz + hz
    const f32x4 Chn = mfma16(Anh.v, Bf.v, zero4);  // hn only
    const f32x4 Cxn = mfma16(Anx.v, Bf.v, zero4);  // xn only
    const f32x4 Cy1 = mfma16(Ay1.v, Bf.v, zero4);  // y1 of step t-1

    // y path for t-1 (independent of recurrence chain)
    doY(Cy1, t - 1);

    // gate epilogue -> h_t
#pragma unroll
    for (int r = 0; r < 4; ++r) {
      const float rr = sigm(Cr[r] + br_[r]);
      const float zz = sigm(Cz[r] + bz_[r]);
      const float nn =
          tanh_fast((Cxn[r] + bin_[r]) + rr * (Chn[r] + bhn_[r]));
      hprev[r] = nn + zz * (hprev[r] - nn);
    }
  };

  for (int t4 = 0; t4 < kT; t4 += 4) {
    doStep(t4 + 0, 0);
    doStep(t4 + 1, 1);
    doStep(t4 + 2, 2);
    doStep(t4 + 3, 3);
  }

  // drain: y for t = kT-1 from final h
  {
    const unsigned P0 = pkbf(hprev[0], hprev[1]);
    const unsigned P1 = pkbf(hprev[2], hprev[3]);
    const int bp0 = __builtin_amdgcn_ds_bpermute(a_lo, (int)P0);
    const int bp1 = __builtin_amdgcn_ds_bpermute(a_lo, (int)P1);
    const int bp2 = __builtin_amdgcn_ds_bpermute(a_hi, (int)P0);
    const int bp3 = __builtin_amdgcn_ds_bpermute(a_hi, (int)P1);
    Frag Bf;
    Bf.u[0] = (qt < 2) ? (unsigned)bp0 : 0u;
    Bf.u[1] = (qt < 2) ? (unsigned)bp1 : 0u;
    Bf.u[2] = (qt < 2) ? (unsigned)bp2 : 0u;
    Bf.u[3] = (qt < 2) ? (unsigned)bp3 : 0u;
    const f32x4 Cy1 = mfma16(Ay1.v, Bf.v, zero4);
    doY(Cy1, kT - 1);
  }
}

extern "C" void kernel_launch(void* const* d_in, const int* in_sizes, int n_in,
                              void* d_out, int out_size, void* d_ws,
                              size_t ws_size, hipStream_t stream) {
  const float* x = (const float*)d_in[0];
  const float* Wih = (const float*)d_in[1];
  const float* Whh = (const float*)d_in[2];
  const float* bih = (const float*)d_in[3];
  const float* bhh = (const float*)d_in[4];
  const float* W1 = (const float*)d_in[5];
  const float* b1 = (const float*)d_in[6];
  const float* W2 = (const float*)d_in[7];
  const float* b2 = (const float*)d_in[8];
  const float* W3 = (const float*)d_in[9];
  const float* b3 = (const float*)d_in[10];
  float* out = (float*)d_out;

  actor_mfma<<<dim3(kN * 8), dim3(64), 0, stream>>>(x, Wih, Whh, bih, bhh, W1,
                                                    b1, W2, b2, W3, b3, out);
}